// Round 8
// baseline (490.413 us; speedup 1.0000x reference)
//
#include <hip/hip_runtime.h>
#include <hip/hip_bf16.h>
#include <math.h>

#define Bx   32
#define Nx   2048
#define Sx   256
#define NSx  16
#define CINx 256

typedef unsigned short u16;
typedef unsigned int   u32;
typedef unsigned long long u64;
typedef short bf16x8 __attribute__((ext_vector_type(8)));
typedef float f32x4  __attribute__((ext_vector_type(4)));
typedef float f32x16 __attribute__((ext_vector_type(16)));

__device__ __forceinline__ float b2f(u16 u) {
  union { u32 i; float f; } v; v.i = ((u32)u) << 16; return v.f;
}
__device__ __forceinline__ u16 f2b(float x) {  // RNE f32->bf16
  u32 u = __float_as_uint(x);
  u32 r = (u + 0x7FFFu + ((u >> 16) & 1u)) >> 16;
  return (u16)r;
}
__device__ __forceinline__ float ldin(const void* p, size_t i, int bf) {
  return bf ? b2f(((const u16*)p)[i]) : ((const float*)p)[i];
}

// block-uniform dtype sniff: all waves ballot the same 64 words -> same result
__device__ __forceinline__ int sniff_bf(const void* xyzR) {
  u32 x = ((const u32*)xyzR)[threadIdx.x & 63];
  int e = (x >> 7) & 0xFF;                 // bf16-exponent field of the low u16
  u64 m = __ballot(e >= 100 && e <= 140);
  return __popcll(m) >= 48;                // bf16 world: ~64/64; f32 world: ~10/64
}

#define DPP_FMAX(x, ctrl)                                                      \
  x = fmaxf(x, __int_as_float(__builtin_amdgcn_update_dpp(                     \
          __float_as_int(x), __float_as_int(x), (ctrl), 0xf, 0xf, false)))

// ---------------- workspace layout (bytes) ----------------
#define OFF_FEATT 0                      // bf16 (B,N,C)   33554432
#define OFF_XT    (33554432)             // f32 (B,S,128)   4194304
#define OFF_T     (OFF_XT + 4194304)     // (unused)        2097152
#define OFF_YT    (OFF_T + 2097152)      // f32 (B,S,128)   4194304
#define OFF_NXYZ  (OFF_YT + 4194304)     // f32 (B,S,3)       98304
#define OFF_IDX   (OFF_NXYZ + 98304)     // (unused)         524288
#define OFF_ATT   (OFF_IDX + 524288)     // (unused)            512
#define OFF_W0F   (OFF_ATT + 512)        // bf16 frag-packed 17*4*64*8
#define OFF_B0    (OFF_W0F + 133120)
#define OFF_W1F   (OFF_B0 + 512)         // bf16 frag-packed 8*4*64*8
#define OFF_B1    (OFF_W1F + 65536)
#define OFF_W2F   (OFF_B1 + 512)
#define OFF_B2    (OFF_W2F + 65536)
#define OFF_WTT   (OFF_B2 + 512)         // f32 128x64 (c-major)
#define OFF_WPT   (OFF_WTT + 32768)
#define OFF_WGT   (OFF_WPT + 32768)
#define OFF_C1T   (OFF_WGT + 32768)      // f32 128x128 (c-major, bn-folded)
#define OFF_D1    (OFF_C1T + 65536)
#define OFF_C2T   (OFF_D1 + 512)
#define OFF_D2    (OFF_C2T + 65536)
#define OFF_C3T   (OFF_D2 + 512)         // f32 128x43 (c-major)
#define OFF_WZF   (OFF_C3T + 22016)      // f32 128x16         8192
#define OFF_GNG   (OFF_WZF + 8192)       // f32 128             512
#define OFF_GNB   (OFF_GNG + 512)
#define OFF_C3B   (OFF_GNB + 512)        // f32 43              512

// ---------------- mega: fps (0..31) + transpose (32..4127) + prep (4128..4191) ----------------
#define TRANS_BLKS 4096
__global__ __launch_bounds__(256) void k_mega(
    const void* __restrict__ xyzR, const void* __restrict__ featR,
    const void* sa_w0, const void* sa_w1, const void* sa_w2,
    const void* sa_g,  const void* sa_b,  const void* sa_m, const void* sa_v,
    const void* wt, const void* wp, const void* wg, const void* wzI,
    const void* gngI, const void* gnbI,
    const void* c1w, const void* c1b,
    const void* bn1g, const void* bn1b, const void* bn1m, const void* bn1v,
    const void* c2w, const void* c2b,
    const void* bn2g, const void* bn2b, const void* bn2m, const void* bn2v,
    const void* c3w, const void* c3bI,
    float* __restrict__ nxyz, u16* __restrict__ featT,
    u16* __restrict__ w0F, float* __restrict__ b0, u16* __restrict__ w1F, float* __restrict__ b1,
    u16* __restrict__ w2F, float* __restrict__ b2,
    float* __restrict__ wtT, float* __restrict__ wpT, float* __restrict__ wgT,
    float* __restrict__ c1T, float* __restrict__ d1, float* __restrict__ c2T, float* __restrict__ d2,
    float* __restrict__ c3T, float* __restrict__ wzF, float* __restrict__ gngF,
    float* __restrict__ gnbF, float* __restrict__ c3bF) {
  __shared__ union {
    struct { float sxyz[Nx * 3]; float rec[2][4][8]; } fps;  // rec: val, idxbits, x, y, z
    u16 tile[64][65];
  } sm;
  int bid = blockIdx.x, t = threadIdx.x;
  int bf = sniff_bf(xyzR);

  if (bid < Bx) {
    // ---------------- FPS: xyz in LDS, DPP argmax, coords carried in reduction record ----------------
    int b = bid;
    const size_t xb = (size_t)b * Nx * 3;
    for (int i = t; i < Nx * 3; i += 256) sm.fps.sxyz[i] = ldin(xyzR, xb + i, bf);
    __syncthreads();
    float px[8], py[8], pz[8], dist[8];
#pragma unroll
    for (int j = 0; j < 8; ++j) {
      int p = t * 8 + j;
      px[j] = sm.fps.sxyz[p * 3 + 0];
      py[j] = sm.fps.sxyz[p * 3 + 1];
      pz[j] = sm.fps.sxyz[p * 3 + 2];
      dist[j] = 1e10f;
    }
    int lane = t & 63, w = t >> 6;
    int far = 0, myind = 0;
    float fcx = sm.fps.sxyz[0], fcy = sm.fps.sxyz[1], fcz = sm.fps.sxyz[2];
    for (int it = 0; it < Sx; ++it) {
      if (t == it) myind = far;                 // scan emits pre-update far
      float bv = -1.f; int bi = 0;
      float bx = 0.f, by = 0.f, bz = 0.f;
#pragma unroll
      for (int j = 0; j < 8; ++j) {
        float dx = __fsub_rn(px[j], fcx);
        float dy = __fsub_rn(py[j], fcy);
        float dz = __fsub_rn(pz[j], fcz);
        float d = __fadd_rn(__fadd_rn(__fmul_rn(dx, dx), __fmul_rn(dy, dy)), __fmul_rn(dz, dz));
        float nd = fminf(dist[j], d);
        dist[j] = nd;
        if (nd > bv) { bv = nd; bi = t * 8 + j; bx = px[j]; by = py[j]; bz = pz[j]; }
      }
      // wave max via DPP; lane 63 holds the wave max
      float x = bv;
      DPP_FMAX(x, 0x111);   // row_shr:1
      DPP_FMAX(x, 0x112);   // row_shr:2
      DPP_FMAX(x, 0x114);   // row_shr:4
      DPP_FMAX(x, 0x118);   // row_shr:8
      DPP_FMAX(x, 0x142);   // row_bcast:15
      DPP_FMAX(x, 0x143);   // row_bcast:31
      float wmax = __int_as_float(__builtin_amdgcn_readlane(__float_as_int(x), 63));
      u64 mk = __ballot(bv == wmax);
      int srcl = (int)__builtin_ctzll(mk);      // lowest lane = lowest point index
      int p = it & 1;
      if (lane == srcl) {                       // winner lane writes its record directly
        float4 r4;
        r4.x = bv;
        r4.y = __uint_as_float((u32)bi);
        r4.z = bx; r4.w = by;
        *(float4*)&sm.fps.rec[p][w][0] = r4;
        sm.fps.rec[p][w][4] = bz;
      }
      __syncthreads();
      // all threads redundantly reduce 4 records (val desc, idx asc tie-break)
      float4 r0 = *(const float4*)&sm.fps.rec[p][0][0]; float z0 = sm.fps.rec[p][0][4];
      float4 r1 = *(const float4*)&sm.fps.rec[p][1][0]; float z1 = sm.fps.rec[p][1][4];
      float4 r2 = *(const float4*)&sm.fps.rec[p][2][0]; float z2 = sm.fps.rec[p][2][4];
      float4 r3 = *(const float4*)&sm.fps.rec[p][3][0]; float z3 = sm.fps.rec[p][3][4];
      bool s01 = (r1.x > r0.x) || (r1.x == r0.x && __float_as_uint(r1.y) < __float_as_uint(r0.y));
      float4 ra = s01 ? r1 : r0; float za = s01 ? z1 : z0;
      bool s23 = (r3.x > r2.x) || (r3.x == r2.x && __float_as_uint(r3.y) < __float_as_uint(r2.y));
      float4 rb = s23 ? r3 : r2; float zb = s23 ? z3 : z2;
      bool sab = (rb.x > ra.x) || (rb.x == ra.x && __float_as_uint(rb.y) < __float_as_uint(ra.y));
      float4 rf = sab ? rb : ra; float zf = sab ? zb : za;
      far = (int)__float_as_uint(rf.y);
      fcx = rf.z; fcy = rf.w; fcz = zf;
    }
    float* o = nxyz + ((size_t)b * Sx + t) * 3;
    o[0] = sm.fps.sxyz[myind * 3 + 0];
    o[1] = sm.fps.sxyz[myind * 3 + 1];
    o[2] = sm.fps.sxyz[myind * 3 + 2];
  } else if (bid < Bx + TRANS_BLKS) {
    // ---------------- feature transpose (B,C,N)->(B,N,C) bf16, 64x64 tiles ----------------
    int tb = bid - Bx;
    int nblk = tb & 31, rest = tb >> 5;
    int cblk = rest & 3, b = rest >> 2;
    int n0 = nblk * 64, c0 = cblk * 64;
    int tx = t & 63, ty = t >> 6;
#pragma unroll
    for (int r = ty; r < 64; r += 4) {
      size_t src = ((size_t)(b * CINx + c0 + r)) * Nx + n0 + tx;
      sm.tile[r][tx] = bf ? ((const u16*)featR)[src] : f2b(((const float*)featR)[src]);
    }
    __syncthreads();
#pragma unroll
    for (int r = ty; r < 64; r += 4)
      featT[((size_t)(b * Nx + n0 + r)) * CINx + c0 + tx] = sm.tile[tx][r];
  } else {
    // prep: B-frag packing for 32x32x16: lane l holds B[k=kt*16+(l>>5)*8+j][n=nt*32+(l&31)]
    int g0 = (bid - Bx - TRANS_BLKS) * 256 + t;
    const int gs = 64 * 256;
    for (int i = g0; i < 17 * 4 * 64 * 8; i += gs) {
      int j = i & 7, lane = (i >> 3) & 63, nt = (i >> 9) & 3, kt = i >> 11;
      int o = nt * 32 + (lane & 31);
      int c = kt * 16 + ((lane >> 5) << 3) + j;
      float s = ldin(sa_g, o, bf) * rsqrtf(ldin(sa_v, o, bf) + 1e-5f);
      float w;
      if (c < 256) w = ldin(sa_w0, o * 259 + 3 + c, bf);
      else if (c < 259) w = ldin(sa_w0, o * 259 + (c - 256), bf);
      else w = 0.f;
      w0F[i] = f2b(w * s);
    }
    for (int i = g0; i < 8 * 4 * 64 * 8; i += gs) {
      int j = i & 7, lane = (i >> 3) & 63, nt = (i >> 9) & 3, kt = i >> 11;
      int o = nt * 32 + (lane & 31);
      int c = kt * 16 + ((lane >> 5) << 3) + j;
      float s1 = ldin(sa_g, 128 + o, bf) * rsqrtf(ldin(sa_v, 128 + o, bf) + 1e-5f);
      float s2 = ldin(sa_g, 256 + o, bf) * rsqrtf(ldin(sa_v, 256 + o, bf) + 1e-5f);
      w1F[i] = f2b(ldin(sa_w1, o * 128 + c, bf) * s1);
      w2F[i] = f2b(ldin(sa_w2, o * 128 + c, bf) * s2);
    }
    for (int o = g0; o < 128; o += gs) {
      float s0 = ldin(sa_g, o, bf)       * rsqrtf(ldin(sa_v, o, bf)       + 1e-5f);
      float s1 = ldin(sa_g, 128 + o, bf) * rsqrtf(ldin(sa_v, 128 + o, bf) + 1e-5f);
      float s2 = ldin(sa_g, 256 + o, bf) * rsqrtf(ldin(sa_v, 256 + o, bf) + 1e-5f);
      b0[o] = ldin(sa_b, o, bf)       - ldin(sa_m, o, bf)       * s0;
      b1[o] = ldin(sa_b, 128 + o, bf) - ldin(sa_m, 128 + o, bf) * s1;
      b2[o] = ldin(sa_b, 256 + o, bf) - ldin(sa_m, 256 + o, bf) * s2;
      float sc1 = ldin(bn1g, o, bf) * rsqrtf(ldin(bn1v, o, bf) + 1e-5f);
      float sc2 = ldin(bn2g, o, bf) * rsqrtf(ldin(bn2v, o, bf) + 1e-5f);
      d1[o] = (ldin(c1b, o, bf) - ldin(bn1m, o, bf)) * sc1 + ldin(bn1b, o, bf);
      d2[o] = (ldin(c2b, o, bf) - ldin(bn2m, o, bf)) * sc2 + ldin(bn2b, o, bf);
      gngF[o] = ldin(gngI, o, bf);
      gnbF[o] = ldin(gnbI, o, bf);
    }
    for (int i = g0; i < 128 * 128; i += gs) {
      int o = i >> 7, c = i & 127;
      float sc1 = ldin(bn1g, o, bf) * rsqrtf(ldin(bn1v, o, bf) + 1e-5f);
      float sc2 = ldin(bn2g, o, bf) * rsqrtf(ldin(bn2v, o, bf) + 1e-5f);
      c1T[c * 128 + o] = ldin(c1w, i, bf) * sc1;
      c2T[c * 128 + o] = ldin(c2w, i, bf) * sc2;
    }
    for (int i = g0; i < 64 * 128; i += gs) {
      int o = i >> 7, c = i & 127;
      wtT[c * 64 + o] = ldin(wt, i, bf);
      wpT[c * 64 + o] = ldin(wp, i, bf);
      wgT[c * 64 + o] = ldin(wg, i, bf);
    }
    for (int i = g0; i < 43 * 128; i += gs) {
      int o = i >> 7, c = i & 127;
      c3T[c * 43 + o] = ldin(c3w, i, bf);
    }
    for (int i = g0; i < 2048; i += gs) wzF[i] = ldin(wzI, i, bf);
    for (int i = g0; i < 43; i += gs) c3bF[i] = ldin(c3bI, i, bf);
  }
}

// ---------------- fused ball query + SA-MLP (32x32x16 MFMA), barrier-free ----------------
__global__ __launch_bounds__(256) void k_fused(
    const u16* __restrict__ featT, const void* __restrict__ xyzR,
    const float* __restrict__ nxyz,
    const u16* __restrict__ w0F, const float* __restrict__ b0v,
    const u16* __restrict__ w1F, const float* __restrict__ b1v,
    const u16* __restrict__ w2F, const float* __restrict__ b2v,
    float* __restrict__ xT) {
  __shared__ __align__(16) u16 hAa[4][32 * 136];   // per-wave activation buffer
  __shared__ int ids[4][32];                        // per-wave neighbor lists
  int bf = sniff_bf(xyzR);
  int t = threadIdx.x, w = t >> 6, lane = t & 63;
  int b = blockIdx.y;
  int s0 = (blockIdx.x * 4 + w) * 2;
  u16* hA = &hAa[w][0];
  int m = lane & 31, half = lane >> 5;
  const size_t xb = (size_t)b * Nx * 3;

  const float* cen0 = nxyz + ((size_t)b * Sx + s0) * 3;
  float c0x = cen0[0], c0y = cen0[1], c0z = cen0[2];
  float c1x = cen0[3], c1y = cen0[4], c1z = cen0[5];

  const float R2 = (float)(0.3 * 0.3);
  u64 below = (lane == 63) ? 0x7fffffffffffffffull : ((1ull << lane) - 1ull);
  int have0 = 0, have1 = 0;
  for (int ch = 0; ch < Nx / 64; ++ch) {
    int p = ch * 64 + lane;
    float px = ldin(xyzR, xb + p * 3 + 0, bf);
    float py = ldin(xyzR, xb + p * 3 + 1, bf);
    float pz = ldin(xyzR, xb + p * 3 + 2, bf);
    float dx0 = __fsub_rn(px, c0x), dy0 = __fsub_rn(py, c0y), dz0 = __fsub_rn(pz, c0z);
    float d0 = __fadd_rn(__fadd_rn(__fmul_rn(dx0, dx0), __fmul_rn(dy0, dy0)), __fmul_rn(dz0, dz0));
    float dx1 = __fsub_rn(px, c1x), dy1 = __fsub_rn(py, c1y), dz1 = __fsub_rn(pz, c1z);
    float d1 = __fadd_rn(__fadd_rn(__fmul_rn(dx1, dx1), __fmul_rn(dy1, dy1)), __fmul_rn(dz1, dz1));
    bool h0 = d0 < R2, h1 = d1 < R2;
    u64 m0 = __ballot(h0), m1 = __ballot(h1);
    if (h0) { int pos = have0 + __popcll(m0 & below); if (pos < NSx) ids[w][pos] = p; }
    if (h1) { int pos = have1 + __popcll(m1 & below); if (pos < NSx) ids[w][16 + pos] = p; }
    have0 += __popcll(m0);
    have1 += __popcll(m1);
  }
  if (lane < 32) {
    int c = lane >> 4, i = lane & 15;
    int hv = c ? have1 : have0;
    if (i >= hv && i < NSx) ids[w][c * 16 + i] = ids[w][c * 16];
  }
  int pn = ids[w][m];

  float pcx = (m >> 4) ? c1x : c0x, pcy = (m >> 4) ? c1y : c0y, pcz = (m >> 4) ? c1z : c0z;
  bf16x8 a_tail = (bf16x8)(short)0;
  {
    float gx = ldin(xyzR, xb + (size_t)pn * 3 + 0, bf);
    float gy = ldin(xyzR, xb + (size_t)pn * 3 + 1, bf);
    float gz = ldin(xyzR, xb + (size_t)pn * 3 + 2, bf);
    if (half == 0) {
      a_tail[0] = (short)f2b((gx - pcx) * (1.0f / 0.3f));
      a_tail[1] = (short)f2b((gy - pcy) * (1.0f / 0.3f));
      a_tail[2] = (short)f2b((gz - pcz) * (1.0f / 0.3f));
    }
  }

  const bf16x8* wf0 = (const bf16x8*)w0F;
  const bf16x8* wf1 = (const bf16x8*)w1F;
  const bf16x8* wf2 = (const bf16x8*)w2F;
  f32x16 acc[4];

#pragma unroll
  for (int nt = 0; nt < 4; ++nt) acc[nt] = (f32x16)(0.f);
  const u16* arow = featT + ((size_t)b * Nx + pn) * CINx + half * 8;
#pragma unroll
  for (int kt = 0; kt < 17; ++kt) {
    bf16x8 a = (kt < 16) ? *(const bf16x8*)(arow + kt * 16) : a_tail;
#pragma unroll
    for (int nt = 0; nt < 4; ++nt)
      acc[nt] = __builtin_amdgcn_mfma_f32_32x32x16_bf16(a, wf0[(kt * 4 + nt) * 64 + lane], acc[nt], 0, 0, 0);
  }
#pragma unroll
  for (int nt = 0; nt < 4; ++nt) {
    float bb = b0v[nt * 32 + m];
#pragma unroll
    for (int r = 0; r < 16; ++r) {
      int mm = (r & 3) + 8 * (r >> 2) + 4 * half;
      hA[mm * 136 + nt * 32 + m] = f2b(fmaxf(acc[nt][r] + bb, 0.f));
    }
  }
#pragma unroll
  for (int nt = 0; nt < 4; ++nt) acc[nt] = (f32x16)(0.f);
#pragma unroll
  for (int kt = 0; kt < 8; ++kt) {
    bf16x8 a = *(const bf16x8*)(hA + m * 136 + kt * 16 + half * 8);
#pragma unroll
    for (int nt = 0; nt < 4; ++nt)
      acc[nt] = __builtin_amdgcn_mfma_f32_32x32x16_bf16(a, wf1[(kt * 4 + nt) * 64 + lane], acc[nt], 0, 0, 0);
  }
#pragma unroll
  for (int nt = 0; nt < 4; ++nt) {
    float bb = b1v[nt * 32 + m];
#pragma unroll
    for (int r = 0; r < 16; ++r) {
      int mm = (r & 3) + 8 * (r >> 2) + 4 * half;
      hA[mm * 136 + nt * 32 + m] = f2b(fmaxf(acc[nt][r] + bb, 0.f));
    }
  }
#pragma unroll
  for (int nt = 0; nt < 4; ++nt) acc[nt] = (f32x16)(0.f);
#pragma unroll
  for (int kt = 0; kt < 8; ++kt) {
    bf16x8 a = *(const bf16x8*)(hA + m * 136 + kt * 16 + half * 8);
#pragma unroll
    for (int nt = 0; nt < 4; ++nt)
      acc[nt] = __builtin_amdgcn_mfma_f32_32x32x16_bf16(a, wf2[(kt * 4 + nt) * 64 + lane], acc[nt], 0, 0, 0);
  }
#pragma unroll
  for (int nt = 0; nt < 4; ++nt) {
    float v0 = acc[nt][0], v1 = acc[nt][8];
#pragma unroll
    for (int r = 1; r < 8; ++r) { v0 = fmaxf(v0, acc[nt][r]); v1 = fmaxf(v1, acc[nt][8 + r]); }
    v0 = fmaxf(v0, __shfl_xor(v0, 32, 64));
    v1 = fmaxf(v1, __shfl_xor(v1, 32, 64));
    int o = nt * 32 + m;
    float vv = half ? v1 : v0;
    xT[((size_t)b * Sx + s0 + half) * 128 + o] = fmaxf(vv + b2v[o], 0.f);
  }
}

__device__ __forceinline__ float blocksum(float v, volatile float* red, int t) {
#pragma unroll
  for (int off = 32; off; off >>= 1) v += __shfl_down(v, off, 64);
  __syncthreads();
  if ((t & 63) == 0) red[t >> 6] = v;
  __syncthreads();
  return red[0] + red[1] + red[2] + red[3];
}

// ---------------- fused t/p/g GEMM + attention + wz + GroupNorm + residual ----------------
__global__ __launch_bounds__(256) void k_tpgn(const float* __restrict__ xT,
                                              const float* __restrict__ wtT,
                                              const float* __restrict__ wpT,
                                              const float* __restrict__ wgT,
                                              const float* __restrict__ wzF,
                                              const float* __restrict__ gngF,
                                              const float* __restrict__ gnbF,
                                              float* __restrict__ yT) {
  __shared__ float xs[64][129];
  __shared__ float tS[16][260];
  __shared__ float wts[3][128][16];
  __shared__ float wzs[32][16];
  __shared__ float red[4];
  int g = blockIdx.x, b = blockIdx.y, t = threadIdx.x;
  for (int i = t; i < 512; i += 256)
    wzs[i >> 4][i & 15] = wzF[(g * 32 + (i >> 4)) * 16 + (i & 15)];
  for (int i = t; i < 128 * 16; i += 256) {
    int c = i >> 4, r2 = i & 15;
    wts[0][c][r2] = wtT[c * 64 + g * 16 + r2];
    wts[1][c][r2] = wpT[c * 64 + g * 16 + r2];
    wts[2][c][r2] = wgT[c * 64 + g * 16 + r2];
  }
  int r = t >> 4, sg = t & 15;
  float attp = 0.f;
  for (int tile = 0; tile < 4; ++tile) {
    {
      int rr = t >> 2, part = (t & 3) * 32;
      const float4* src = (const float4*)(xT + ((size_t)b * Sx + tile * 64 + rr) * 128 + part);
#pragma unroll
      for (int q = 0; q < 8; ++q) {
        float4 v = src[q];
        xs[rr][part + q * 4 + 0] = v.x;
        xs[rr][part + q * 4 + 1] = v.y;
        xs[rr][part + q * 4 + 2] = v.z;
        xs[rr][part + q * 4 + 3] = v.w;
      }
    }
    __syncthreads();
    float ta[4], pa[4], ga[4];
#pragma unroll
    for (int j = 0; j < 4; ++j) { ta[j] = 0.f; pa[j] = 0.f; ga[j] = 0.f; }
    for (int c = 0; c < 128; ++c) {
      float wa = wts[0][c][r];
      float wb = wts[1][c][r];
      float wc = wts[2][c][r];
#pragma unroll
      for (int j = 0; j < 4; ++j) {
        float xv = xs[sg * 4 + j][c];
        ta[j] = fmaf(wa, xv, ta[j]);
        pa[j] = fmaf(wb, xv, pa[j]);
        ga[j] = fmaf(wc, xv, ga[j]);
      }
    }
#pragma unroll
    for (int j = 0; j < 4; ++j) {
      attp += pa[j] * ga[j];
      tS[r][tile * 64 + sg * 4 + j] = ta[j];
    }
    __syncthreads();
  }
  float attv = blocksum(attp, red, t);
  int s = t;
  float yv[32];
#pragma unroll
  for (int o = 0; o < 32; ++o) yv[o] = 0.f;
  for (int c = 0; c < 16; ++c) {
    float tv = attv * tS[c][s];
#pragma unroll
    for (int o = 0; o < 32; ++o) yv[o] = fmaf(wzs[o][c], tv, yv[o]);
  }
  float ls = 0.f;
#pragma unroll
  for (int o = 0; o < 32; ++o) ls += yv[o];
  float mu = blocksum(ls, red, t) * (1.f / 8192.f);
  float lq = 0.f;
#pragma unroll
  for (int o = 0; o < 32; ++o) { float d = yv[o] - mu; lq = fmaf(d, d, lq); }
  float var = blocksum(lq, red, t) * (1.f / 8192.f);
  float rs = rsqrtf(var + 1e-5f);
  const float* xrow = xT + ((size_t)b * Sx + s) * 128 + g * 32;
  float* yrow = yT + ((size_t)b * Sx + s) * 128 + g * 32;
#pragma unroll
  for (int o = 0; o < 32; ++o) {
    int ch = g * 32 + o;
    yrow[o] = (yv[o] - mu) * rs * gngF[ch] + gnbF[ch] + xrow[o];
  }
}

// ---------------- FFN + box-head output assembly ----------------
__global__ __launch_bounds__(256) void k_ffn(const float* __restrict__ yT,
                                             const float* __restrict__ c1T, const float* __restrict__ d1,
                                             const float* __restrict__ c2T, const float* __restrict__ d2,
                                             const float* __restrict__ c3T, const float* __restrict__ c3bF,
                                             const float* __restrict__ nxyz,
                                             const void* __restrict__ xyzR,
                                             void* __restrict__ outp) {
  __shared__ float ys[32][132];
  __shared__ float h1s[32][132];
  __shared__ float h2s[32][132];
  __shared__ float nets[32][44];
  int bf = sniff_bf(xyzR);
  int b = blockIdx.y, s0 = blockIdx.x * 32, t = threadIdx.x;
  {
    int r = t >> 3, part = (t & 7) * 16;
    const float4* src = (const float4*)(yT + ((size_t)b * Sx + s0 + r) * 128 + part);
#pragma unroll
    for (int q = 0; q < 4; ++q) *(float4*)&ys[r][part + q * 4] = src[q];
  }
  __syncthreads();
  int o0 = (t & 31) * 4, sl0 = (t >> 5) * 4;
  float acc[16];
#pragma unroll
  for (int k = 0; k < 16; ++k) acc[k] = 0.f;
  for (int c = 0; c < 128; ++c) {
    float4 wv = *(const float4*)(c1T + c * 128 + o0);
    float yv[4];
#pragma unroll
    for (int j = 0; j < 4; ++j) yv[j] = ys[sl0 + j][c];
#pragma unroll
    for (int j = 0; j < 4; ++j) {
      acc[0 * 4 + j] = fmaf(wv.x, yv[j], acc[0 * 4 + j]);
      acc[1 * 4 + j] = fmaf(wv.y, yv[j], acc[1 * 4 + j]);
      acc[2 * 4 + j] = fmaf(wv.z, yv[j], acc[2 * 4 + j]);
      acc[3 * 4 + j] = fmaf(wv.w, yv[j], acc[3 * 4 + j]);
    }
  }
  {
    float4 dv = *(const float4*)(d1 + o0);
    float db[4] = {dv.x, dv.y, dv.z, dv.w};
#pragma unroll
    for (int i = 0; i < 4; ++i)
#pragma unroll
      for (int j = 0; j < 4; ++j)
        h1s[sl0 + j][o0 + i] = fmaxf(acc[i * 4 + j] + db[i], 0.f);
  }
  __syncthreads();
#pragma unroll
  for (int k = 0; k < 16; ++k) acc[k] = 0.f;
  for (int c = 0; c < 128; ++c) {
    float4 wv = *(const float4*)(c2T + c * 128 + o0);
    float yv[4];
#pragma unroll
    for (int j = 0; j < 4; ++j) yv[j] = h1s[sl0 + j][c];
#pragma unroll
    for (int j = 0; j < 4; ++j) {
      acc[0 * 4 + j] = fmaf(wv.x, yv[j], acc[0 * 4 + j]);
      acc[1 * 4 + j] = fmaf(wv.y, yv[j], acc[1 * 4 + j]);
      acc[2 * 4 + j] = fmaf(wv.z, yv[j], acc[2 * 4 + j]);
      acc[3 * 4 + j] = fmaf(wv.w, yv[j], acc[3 * 4 + j]);
    }
  }
  {
    float4 dv = *(const float4*)(d2 + o0);
    float db[4] = {dv.x, dv.y, dv.z, dv.w};
#pragma unroll
    for (int i = 0; i < 4; ++i)
#pragma unroll
      for (int j = 0; j < 4; ++j)
        h2s[sl0 + j][o0 + i] = fmaxf(acc[i * 4 + j] + db[i], 0.f);
  }
  __syncthreads();
  for (int f = t; f < 43 * 32; f += 256) {
    int o = f >> 5, s = f & 31;
    float a = c3bF[o];
    for (int c4 = 0; c4 < 32; ++c4) {
      float4 hv = *(const float4*)&h2s[s][c4 * 4];
      a = fmaf(hv.x, c3T[(c4 * 4 + 0) * 43 + o], a);
      a = fmaf(hv.y, c3T[(c4 * 4 + 1) * 43 + o], a);
      a = fmaf(hv.z, c3T[(c4 * 4 + 2) * 43 + o], a);
      a = fmaf(hv.w, c3T[(c4 * 4 + 3) * 43 + o], a);
    }
    nets[s][o] = a;
  }
  __syncthreads();
  const float PI12 = (float)(M_PI / 12.0);
  for (int f = t; f < 55 * 32; f += 256) {
    int s = f / 55, kk = f - s * 55;
    float v;
    if (kk < 5) {
      v = nets[s][kk];
      if (kk >= 2) v += nxyz[((size_t)b * Sx + s0 + s) * 3 + (kk - 2)];
    } else if (kk < 31) v = nets[s][kk];
    else if (kk < 43) v = nets[s][kk - 12] * PI12;
    else v = nets[s][kk - 12];
    size_t oi = ((size_t)b * Sx + s0 + s) * 55 + kk;
    if (bf) ((u16*)outp)[oi] = f2b(v);
    else    ((float*)outp)[oi] = v;
  }
}

extern "C" void kernel_launch(void* const* d_in, const int* in_sizes, int n_in,
                              void* d_out, int out_size, void* d_ws, size_t ws_size,
                              hipStream_t stream) {
  char* w = (char*)d_ws;
  u16*   featT = (u16*)(w + OFF_FEATT);
  float* xT    = (float*)(w + OFF_XT);
  float* yT    = (float*)(w + OFF_YT);
  float* nxyz  = (float*)(w + OFF_NXYZ);
  u16*   w0F   = (u16*)(w + OFF_W0F);
  float* b0    = (float*)(w + OFF_B0);
  u16*   w1F   = (u16*)(w + OFF_W1F);
  float* b1    = (float*)(w + OFF_B1);
  u16*   w2F   = (u16*)(w + OFF_W2F);
  float* b2    = (float*)(w + OFF_B2);
  float* wtT   = (float*)(w + OFF_WTT);
  float* wpT   = (float*)(w + OFF_WPT);
  float* wgT   = (float*)(w + OFF_WGT);
  float* c1T   = (float*)(w + OFF_C1T);
  float* d1    = (float*)(w + OFF_D1);
  float* c2T   = (float*)(w + OFF_C2T);
  float* d2    = (float*)(w + OFF_D2);
  float* c3T   = (float*)(w + OFF_C3T);
  float* wzF   = (float*)(w + OFF_WZF);
  float* gngF  = (float*)(w + OFF_GNG);
  float* gnbF  = (float*)(w + OFF_GNB);
  float* c3bF  = (float*)(w + OFF_C3B);

  k_mega<<<Bx + TRANS_BLKS + 64, 256, 0, stream>>>(
      d_in[0], d_in[1],
      d_in[2], d_in[3], d_in[4], d_in[5], d_in[6], d_in[7], d_in[8],
      d_in[9], d_in[10], d_in[11], d_in[12], d_in[13], d_in[14],
      d_in[15], d_in[16], d_in[17], d_in[18], d_in[19], d_in[20],
      d_in[21], d_in[22], d_in[23], d_in[24], d_in[25], d_in[26],
      d_in[27], d_in[28],
      nxyz, featT,
      w0F, b0, w1F, b1, w2F, b2, wtT, wpT, wgT,
      c1T, d1, c2T, d2, c3T, wzF, gngF, gnbF, c3bF);
  k_fused<<<dim3(Sx / 8, Bx), 256, 0, stream>>>(featT, d_in[0], nxyz,
                                                w0F, b0, w1F, b1, w2F, b2, xT);
  k_tpgn<<<dim3(4, Bx), 256, 0, stream>>>(xT, wtT, wpT, wgT, wzF, gngF, gnbF, yT);
  k_ffn<<<dim3(8, Bx), 256, 0, stream>>>(yT, c1T, d1, c2T, d2, c3T, c3bF, nxyz,
                                         d_in[0], d_out);
}

// Round 9
// 428.554 us; speedup vs baseline: 1.1443x; 1.1443x over previous
//
#include <hip/hip_runtime.h>
#include <hip/hip_bf16.h>
#include <math.h>

#define Bx   32
#define Nx   2048
#define Sx   256
#define NSx  16
#define CINx 256

typedef unsigned short u16;
typedef unsigned int   u32;
typedef unsigned long long u64;
typedef short bf16x8 __attribute__((ext_vector_type(8)));
typedef float f32x4  __attribute__((ext_vector_type(4)));
typedef float f32x16 __attribute__((ext_vector_type(16)));

__device__ __forceinline__ float b2f(u16 u) {
  union { u32 i; float f; } v; v.i = ((u32)u) << 16; return v.f;
}
__device__ __forceinline__ u16 f2b(float x) {  // RNE f32->bf16
  u32 u = __float_as_uint(x);
  u32 r = (u + 0x7FFFu + ((u >> 16) & 1u)) >> 16;
  return (u16)r;
}
__device__ __forceinline__ float ldin(const void* p, size_t i, int bf) {
  return bf ? b2f(((const u16*)p)[i]) : ((const float*)p)[i];
}

#define DPP_FMAX(x, ctrl)                                                      \
  x = fmaxf(x, __int_as_float(__builtin_amdgcn_update_dpp(                     \
          __float_as_int(x), __float_as_int(x), (ctrl), 0xf, 0xf, false)))

// ---------------- workspace layout (bytes) ----------------
#define OFF_FEATT 0                      // bf16 (B,N,C)   33554432
#define OFF_XT    (33554432)             // f32 (B,S,128)   4194304
#define OFF_T     (OFF_XT + 4194304)     // (unused)        2097152
#define OFF_YT    (OFF_T + 2097152)      // f32 (B,S,128)   4194304
#define OFF_NXYZ  (OFF_YT + 4194304)     // f32 (B,S,3)       98304
#define OFF_IDX   (OFF_NXYZ + 98304)     // (unused)         524288
#define OFF_ATT   (OFF_IDX + 524288)     // (unused)            512
#define OFF_W0F   (OFF_ATT + 512)        // bf16 frag-packed 17*4*64*8
#define OFF_B0    (OFF_W0F + 133120)
#define OFF_W1F   (OFF_B0 + 512)         // bf16 frag-packed 8*4*64*8
#define OFF_B1    (OFF_W1F + 65536)
#define OFF_W2F   (OFF_B1 + 512)
#define OFF_B2    (OFF_W2F + 65536)
#define OFF_WTT   (OFF_B2 + 512)         // f32 128x64 (c-major)
#define OFF_WPT   (OFF_WTT + 32768)
#define OFF_WGT   (OFF_WPT + 32768)
#define OFF_C1T   (OFF_WGT + 32768)      // f32 128x128 (c-major, bn-folded)
#define OFF_D1    (OFF_C1T + 65536)
#define OFF_C2T   (OFF_D1 + 512)
#define OFF_D2    (OFF_C2T + 65536)
#define OFF_C3T   (OFF_D2 + 512)         // f32 128x43 (c-major)
#define OFF_WZF   (OFF_C3T + 22016)      // f32 128x16         8192
#define OFF_GNG   (OFF_WZF + 8192)       // f32 128             512
#define OFF_GNB   (OFF_GNG + 512)
#define OFF_C3B   (OFF_GNB + 512)        // f32 43              512
#define OFF_FLAG  (OFF_C3B + 512)        // i32                 512

// ---------------- dtype sniff ----------------
__global__ __launch_bounds__(256) void k_sniff(const u32* __restrict__ w, int* __restrict__ flag) {
  __shared__ int cnt;
  int t = threadIdx.x;
  if (t == 0) cnt = 0;
  __syncthreads();
  u32 x = w[t];
  int e_lo = (x >> 7) & 0xFF;
  if (e_lo >= 100 && e_lo <= 140) atomicAdd(&cnt, 1);
  __syncthreads();
  if (t == 0) *flag = (cnt > 128) ? 1 : 0;    // 1 = inputs are bf16
}

// ---------------- mega: fps (0..31) + transpose (32..4127) + prep (4128..4191) ----------------
#define TRANS_BLKS 4096
__global__ __launch_bounds__(256) void k_mega(
    const void* __restrict__ xyzR, const void* __restrict__ featR,
    const void* sa_w0, const void* sa_w1, const void* sa_w2,
    const void* sa_g,  const void* sa_b,  const void* sa_m, const void* sa_v,
    const void* wt, const void* wp, const void* wg, const void* wzI,
    const void* gngI, const void* gnbI,
    const void* c1w, const void* c1b,
    const void* bn1g, const void* bn1b, const void* bn1m, const void* bn1v,
    const void* c2w, const void* c2b,
    const void* bn2g, const void* bn2b, const void* bn2m, const void* bn2v,
    const void* c3w, const void* c3bI,
    float* __restrict__ nxyz, u16* __restrict__ featT,
    u16* __restrict__ w0F, float* __restrict__ b0, u16* __restrict__ w1F, float* __restrict__ b1,
    u16* __restrict__ w2F, float* __restrict__ b2,
    float* __restrict__ wtT, float* __restrict__ wpT, float* __restrict__ wgT,
    float* __restrict__ c1T, float* __restrict__ d1, float* __restrict__ c2T, float* __restrict__ d2,
    float* __restrict__ c3T, float* __restrict__ wzF, float* __restrict__ gngF,
    float* __restrict__ gnbF, float* __restrict__ c3bF,
    const int* __restrict__ flagp) {
  __shared__ union {
    struct { float sxyz[Nx * 3]; u64 red[2][4]; } fps;
    u16 tile[64][65];
  } sm;
  int bid = blockIdx.x, t = threadIdx.x;
  int bf = *flagp;

  if (bid < Bx) {
    int b = bid;
    const size_t xb = (size_t)b * Nx * 3;
    for (int i = t; i < Nx * 3; i += 256) sm.fps.sxyz[i] = ldin(xyzR, xb + i, bf);
    __syncthreads();
    float px[8], py[8], pz[8], dist[8];
#pragma unroll
    for (int j = 0; j < 8; ++j) {
      int p = t * 8 + j;
      px[j] = sm.fps.sxyz[p * 3 + 0];
      py[j] = sm.fps.sxyz[p * 3 + 1];
      pz[j] = sm.fps.sxyz[p * 3 + 2];
      dist[j] = 1e10f;
    }
    int lane = t & 63, w = t >> 6;
    int far = 0, myind = 0;
    for (int it = 0; it < Sx; ++it) {
      if (t == it) myind = far;
      float cx = sm.fps.sxyz[far * 3 + 0];
      float cy = sm.fps.sxyz[far * 3 + 1];
      float cz = sm.fps.sxyz[far * 3 + 2];
      float bv = -1.f; int bj = 0;
#pragma unroll
      for (int j = 0; j < 8; ++j) {
        float dx = __fsub_rn(px[j], cx);
        float dy = __fsub_rn(py[j], cy);
        float dz = __fsub_rn(pz[j], cz);
        float d = __fadd_rn(__fadd_rn(__fmul_rn(dx, dx), __fmul_rn(dy, dy)), __fmul_rn(dz, dz));
        float nd = fminf(dist[j], d);
        dist[j] = nd;
        if (nd > bv) { bv = nd; bj = j; }
      }
      int bi = t * 8 + bj;
      float x = bv;
      DPP_FMAX(x, 0x111);
      DPP_FMAX(x, 0x112);
      DPP_FMAX(x, 0x114);
      DPP_FMAX(x, 0x118);
      DPP_FMAX(x, 0x142);
      DPP_FMAX(x, 0x143);
      float wmax = __int_as_float(__builtin_amdgcn_readlane(__float_as_int(x), 63));
      u64 mk = __ballot(bv == wmax);
      int srcl = (int)__builtin_ctzll(mk);
      int wbi = __builtin_amdgcn_readlane(bi, srcl);
      if (lane == 63)
        sm.fps.red[it & 1][w] = ((u64)__float_as_uint(wmax) << 32) | (u32)(~wbi);
      __syncthreads();
      u64 k0 = sm.fps.red[it & 1][0], k1 = sm.fps.red[it & 1][1];
      u64 k2 = sm.fps.red[it & 1][2], k3 = sm.fps.red[it & 1][3];
      u64 best = k0 > k1 ? k0 : k1;
      if (k2 > best) best = k2;
      if (k3 > best) best = k3;
      far = (int)(u32)(~(u32)best);
    }
    float* o = nxyz + ((size_t)b * Sx + t) * 3;
    o[0] = sm.fps.sxyz[myind * 3 + 0];
    o[1] = sm.fps.sxyz[myind * 3 + 1];
    o[2] = sm.fps.sxyz[myind * 3 + 2];
  } else if (bid < Bx + TRANS_BLKS) {
    int tb = bid - Bx;
    int nblk = tb & 31, rest = tb >> 5;
    int cblk = rest & 3, b = rest >> 2;
    int n0 = nblk * 64, c0 = cblk * 64;
    int tx = t & 63, ty = t >> 6;
#pragma unroll
    for (int r = ty; r < 64; r += 4) {
      size_t src = ((size_t)(b * CINx + c0 + r)) * Nx + n0 + tx;
      sm.tile[r][tx] = bf ? ((const u16*)featR)[src] : f2b(((const float*)featR)[src]);
    }
    __syncthreads();
#pragma unroll
    for (int r = ty; r < 64; r += 4)
      featT[((size_t)(b * Nx + n0 + r)) * CINx + c0 + tx] = sm.tile[tx][r];
  } else {
    // prep: B-frag packing for 32x32x16: lane l holds B[k=kt*16+(l>>5)*8+j][n=nt*32+(l&31)]
    int g0 = (bid - Bx - TRANS_BLKS) * 256 + t;
    const int gs = 64 * 256;
    for (int i = g0; i < 17 * 4 * 64 * 8; i += gs) {
      int j = i & 7, lane = (i >> 3) & 63, nt = (i >> 9) & 3, kt = i >> 11;
      int o = nt * 32 + (lane & 31);
      int c = kt * 16 + ((lane >> 5) << 3) + j;
      float s = ldin(sa_g, o, bf) * rsqrtf(ldin(sa_v, o, bf) + 1e-5f);
      float w;
      if (c < 256) w = ldin(sa_w0, o * 259 + 3 + c, bf);
      else if (c < 259) w = ldin(sa_w0, o * 259 + (c - 256), bf);
      else w = 0.f;
      w0F[i] = f2b(w * s);
    }
    for (int i = g0; i < 8 * 4 * 64 * 8; i += gs) {
      int j = i & 7, lane = (i >> 3) & 63, nt = (i >> 9) & 3, kt = i >> 11;
      int o = nt * 32 + (lane & 31);
      int c = kt * 16 + ((lane >> 5) << 3) + j;
      float s1 = ldin(sa_g, 128 + o, bf) * rsqrtf(ldin(sa_v, 128 + o, bf) + 1e-5f);
      float s2 = ldin(sa_g, 256 + o, bf) * rsqrtf(ldin(sa_v, 256 + o, bf) + 1e-5f);
      w1F[i] = f2b(ldin(sa_w1, o * 128 + c, bf) * s1);
      w2F[i] = f2b(ldin(sa_w2, o * 128 + c, bf) * s2);
    }
    for (int o = g0; o < 128; o += gs) {
      float s0 = ldin(sa_g, o, bf)       * rsqrtf(ldin(sa_v, o, bf)       + 1e-5f);
      float s1 = ldin(sa_g, 128 + o, bf) * rsqrtf(ldin(sa_v, 128 + o, bf) + 1e-5f);
      float s2 = ldin(sa_g, 256 + o, bf) * rsqrtf(ldin(sa_v, 256 + o, bf) + 1e-5f);
      b0[o] = ldin(sa_b, o, bf)       - ldin(sa_m, o, bf)       * s0;
      b1[o] = ldin(sa_b, 128 + o, bf) - ldin(sa_m, 128 + o, bf) * s1;
      b2[o] = ldin(sa_b, 256 + o, bf) - ldin(sa_m, 256 + o, bf) * s2;
      float sc1 = ldin(bn1g, o, bf) * rsqrtf(ldin(bn1v, o, bf) + 1e-5f);
      float sc2 = ldin(bn2g, o, bf) * rsqrtf(ldin(bn2v, o, bf) + 1e-5f);
      d1[o] = (ldin(c1b, o, bf) - ldin(bn1m, o, bf)) * sc1 + ldin(bn1b, o, bf);
      d2[o] = (ldin(c2b, o, bf) - ldin(bn2m, o, bf)) * sc2 + ldin(bn2b, o, bf);
      gngF[o] = ldin(gngI, o, bf);
      gnbF[o] = ldin(gnbI, o, bf);
    }
    for (int i = g0; i < 128 * 128; i += gs) {
      int o = i >> 7, c = i & 127;
      float sc1 = ldin(bn1g, o, bf) * rsqrtf(ldin(bn1v, o, bf) + 1e-5f);
      float sc2 = ldin(bn2g, o, bf) * rsqrtf(ldin(bn2v, o, bf) + 1e-5f);
      c1T[c * 128 + o] = ldin(c1w, i, bf) * sc1;
      c2T[c * 128 + o] = ldin(c2w, i, bf) * sc2;
    }
    for (int i = g0; i < 64 * 128; i += gs) {
      int o = i >> 7, c = i & 127;
      wtT[c * 64 + o] = ldin(wt, i, bf);
      wpT[c * 64 + o] = ldin(wp, i, bf);
      wgT[c * 64 + o] = ldin(wg, i, bf);
    }
    for (int i = g0; i < 43 * 128; i += gs) {
      int o = i >> 7, c = i & 127;
      c3T[c * 43 + o] = ldin(c3w, i, bf);
    }
    for (int i = g0; i < 2048; i += gs) wzF[i] = ldin(wzI, i, bf);
    for (int i = g0; i < 43; i += gs) c3bF[i] = ldin(c3bI, i, bf);
  }
}

// ---------------- fused ball query + SA-MLP (32x32x16 MFMA), barrier-free ----------------
__global__ __launch_bounds__(256) void k_fused(
    const u16* __restrict__ featT, const void* __restrict__ xyzR,
    const float* __restrict__ nxyz,
    const u16* __restrict__ w0F, const float* __restrict__ b0v,
    const u16* __restrict__ w1F, const float* __restrict__ b1v,
    const u16* __restrict__ w2F, const float* __restrict__ b2v,
    float* __restrict__ xT, const int* __restrict__ flagp) {
  __shared__ __align__(16) u16 hAa[4][32 * 136];   // per-wave activation buffer
  __shared__ int ids[4][32];                        // per-wave neighbor lists
  int bf = *flagp;
  int t = threadIdx.x, w = t >> 6, lane = t & 63;
  int b = blockIdx.y;
  int s0 = (blockIdx.x * 4 + w) * 2;
  u16* hA = &hAa[w][0];
  int m = lane & 31, half = lane >> 5;
  const size_t xb = (size_t)b * Nx * 3;

  const float* cen0 = nxyz + ((size_t)b * Sx + s0) * 3;
  float c0x = cen0[0], c0y = cen0[1], c0z = cen0[2];
  float c1x = cen0[3], c1y = cen0[4], c1z = cen0[5];

  const float R2 = (float)(0.3 * 0.3);
  u64 below = (lane == 63) ? 0x7fffffffffffffffull : ((1ull << lane) - 1ull);
  int have0 = 0, have1 = 0;
  for (int ch = 0; ch < Nx / 64; ++ch) {
    int p = ch * 64 + lane;
    float px = ldin(xyzR, xb + p * 3 + 0, bf);
    float py = ldin(xyzR, xb + p * 3 + 1, bf);
    float pz = ldin(xyzR, xb + p * 3 + 2, bf);
    float dx0 = __fsub_rn(px, c0x), dy0 = __fsub_rn(py, c0y), dz0 = __fsub_rn(pz, c0z);
    float d0 = __fadd_rn(__fadd_rn(__fmul_rn(dx0, dx0), __fmul_rn(dy0, dy0)), __fmul_rn(dz0, dz0));
    float dx1 = __fsub_rn(px, c1x), dy1 = __fsub_rn(py, c1y), dz1 = __fsub_rn(pz, c1z);
    float d1 = __fadd_rn(__fadd_rn(__fmul_rn(dx1, dx1), __fmul_rn(dy1, dy1)), __fmul_rn(dz1, dz1));
    bool h0 = d0 < R2, h1 = d1 < R2;
    u64 m0 = __ballot(h0), m1 = __ballot(h1);
    if (h0) { int pos = have0 + __popcll(m0 & below); if (pos < NSx) ids[w][pos] = p; }
    if (h1) { int pos = have1 + __popcll(m1 & below); if (pos < NSx) ids[w][16 + pos] = p; }
    have0 += __popcll(m0);
    have1 += __popcll(m1);
  }
  if (lane < 32) {
    int c = lane >> 4, i = lane & 15;
    int hv = c ? have1 : have0;
    if (i >= hv && i < NSx) ids[w][c * 16 + i] = ids[w][c * 16];
  }
  int pn = ids[w][m];

  float pcx = (m >> 4) ? c1x : c0x, pcy = (m >> 4) ? c1y : c0y, pcz = (m >> 4) ? c1z : c0z;
  bf16x8 a_tail = (bf16x8)(short)0;
  {
    float gx = ldin(xyzR, xb + (size_t)pn * 3 + 0, bf);
    float gy = ldin(xyzR, xb + (size_t)pn * 3 + 1, bf);
    float gz = ldin(xyzR, xb + (size_t)pn * 3 + 2, bf);
    if (half == 0) {
      a_tail[0] = (short)f2b((gx - pcx) * (1.0f / 0.3f));
      a_tail[1] = (short)f2b((gy - pcy) * (1.0f / 0.3f));
      a_tail[2] = (short)f2b((gz - pcz) * (1.0f / 0.3f));
    }
  }

  const bf16x8* wf0 = (const bf16x8*)w0F;
  const bf16x8* wf1 = (const bf16x8*)w1F;
  const bf16x8* wf2 = (const bf16x8*)w2F;
  f32x16 acc[4];

#pragma unroll
  for (int nt = 0; nt < 4; ++nt) acc[nt] = (f32x16)(0.f);
  const u16* arow = featT + ((size_t)b * Nx + pn) * CINx + half * 8;
#pragma unroll
  for (int kt = 0; kt < 17; ++kt) {
    bf16x8 a = (kt < 16) ? *(const bf16x8*)(arow + kt * 16) : a_tail;
#pragma unroll
    for (int nt = 0; nt < 4; ++nt)
      acc[nt] = __builtin_amdgcn_mfma_f32_32x32x16_bf16(a, wf0[(kt * 4 + nt) * 64 + lane], acc[nt], 0, 0, 0);
  }
#pragma unroll
  for (int nt = 0; nt < 4; ++nt) {
    float bb = b0v[nt * 32 + m];
#pragma unroll
    for (int r = 0; r < 16; ++r) {
      int mm = (r & 3) + 8 * (r >> 2) + 4 * half;
      hA[mm * 136 + nt * 32 + m] = f2b(fmaxf(acc[nt][r] + bb, 0.f));
    }
  }
#pragma unroll
  for (int nt = 0; nt < 4; ++nt) acc[nt] = (f32x16)(0.f);
#pragma unroll
  for (int kt = 0; kt < 8; ++kt) {
    bf16x8 a = *(const bf16x8*)(hA + m * 136 + kt * 16 + half * 8);
#pragma unroll
    for (int nt = 0; nt < 4; ++nt)
      acc[nt] = __builtin_amdgcn_mfma_f32_32x32x16_bf16(a, wf1[(kt * 4 + nt) * 64 + lane], acc[nt], 0, 0, 0);
  }
#pragma unroll
  for (int nt = 0; nt < 4; ++nt) {
    float bb = b1v[nt * 32 + m];
#pragma unroll
    for (int r = 0; r < 16; ++r) {
      int mm = (r & 3) + 8 * (r >> 2) + 4 * half;
      hA[mm * 136 + nt * 32 + m] = f2b(fmaxf(acc[nt][r] + bb, 0.f));
    }
  }
#pragma unroll
  for (int nt = 0; nt < 4; ++nt) acc[nt] = (f32x16)(0.f);
#pragma unroll
  for (int kt = 0; kt < 8; ++kt) {
    bf16x8 a = *(const bf16x8*)(hA + m * 136 + kt * 16 + half * 8);
#pragma unroll
    for (int nt = 0; nt < 4; ++nt)
      acc[nt] = __builtin_amdgcn_mfma_f32_32x32x16_bf16(a, wf2[(kt * 4 + nt) * 64 + lane], acc[nt], 0, 0, 0);
  }
#pragma unroll
  for (int nt = 0; nt < 4; ++nt) {
    float v0 = acc[nt][0], v1 = acc[nt][8];
#pragma unroll
    for (int r = 1; r < 8; ++r) { v0 = fmaxf(v0, acc[nt][r]); v1 = fmaxf(v1, acc[nt][8 + r]); }
    v0 = fmaxf(v0, __shfl_xor(v0, 32, 64));
    v1 = fmaxf(v1, __shfl_xor(v1, 32, 64));
    int o = nt * 32 + m;
    float vv = half ? v1 : v0;
    xT[((size_t)b * Sx + s0 + half) * 128 + o] = fmaxf(vv + b2v[o], 0.f);
  }
}

__device__ __forceinline__ float blocksum(float v, volatile float* red, int t) {
#pragma unroll
  for (int off = 32; off; off >>= 1) v += __shfl_down(v, off, 64);
  __syncthreads();
  if ((t & 63) == 0) red[t >> 6] = v;
  __syncthreads();
  return red[0] + red[1] + red[2] + red[3];
}

// ---------------- fused t/p/g GEMM + attention + wz + GroupNorm + residual ----------------
// wts r-major [3][16][132] so the c-loop reads are ds_read_b128
__global__ __launch_bounds__(256) void k_tpgn(const float* __restrict__ xT,
                                              const float* __restrict__ wtT,
                                              const float* __restrict__ wpT,
                                              const float* __restrict__ wgT,
                                              const float* __restrict__ wzF,
                                              const float* __restrict__ gngF,
                                              const float* __restrict__ gnbF,
                                              float* __restrict__ yT) {
  __shared__ float xs[64][129];
  __shared__ float tS[16][260];
  __shared__ __align__(16) float wts[3][16][132];
  __shared__ float wzs[32][16];
  __shared__ float red[4];
  int g = blockIdx.x, b = blockIdx.y, t = threadIdx.x;
  for (int i = t; i < 512; i += 256)
    wzs[i >> 4][i & 15] = wzF[(g * 32 + (i >> 4)) * 16 + (i & 15)];
  for (int i = t; i < 128 * 16; i += 256) {
    int c = i >> 4, r2 = i & 15;
    wts[0][r2][c] = wtT[c * 64 + g * 16 + r2];
    wts[1][r2][c] = wpT[c * 64 + g * 16 + r2];
    wts[2][r2][c] = wgT[c * 64 + g * 16 + r2];
  }
  int r = t >> 4, sg = t & 15;
  float attp = 0.f;
  for (int tile = 0; tile < 4; ++tile) {
    {
      int rr = t >> 2, part = (t & 3) * 32;
      const float4* src = (const float4*)(xT + ((size_t)b * Sx + tile * 64 + rr) * 128 + part);
#pragma unroll
      for (int q = 0; q < 8; ++q) {
        float4 v = src[q];
        xs[rr][part + q * 4 + 0] = v.x;
        xs[rr][part + q * 4 + 1] = v.y;
        xs[rr][part + q * 4 + 2] = v.z;
        xs[rr][part + q * 4 + 3] = v.w;
      }
    }
    __syncthreads();
    float ta[4], pa[4], ga[4];
#pragma unroll
    for (int j = 0; j < 4; ++j) { ta[j] = 0.f; pa[j] = 0.f; ga[j] = 0.f; }
    for (int c4 = 0; c4 < 32; ++c4) {
      float4 wa = *(const float4*)&wts[0][r][c4 * 4];
      float4 wb = *(const float4*)&wts[1][r][c4 * 4];
      float4 wc = *(const float4*)&wts[2][r][c4 * 4];
      float4 xr[4];
#pragma unroll
      for (int j = 0; j < 4; ++j) xr[j] = *(const float4*)&xs[sg * 4 + j][c4 * 4];
      // cc ascending keeps the exact accumulation order of the scalar loop
#pragma unroll
      for (int j = 0; j < 4; ++j) {
        ta[j] = fmaf(wa.x, xr[j].x, ta[j]);
        pa[j] = fmaf(wb.x, xr[j].x, pa[j]);
        ga[j] = fmaf(wc.x, xr[j].x, ga[j]);
        ta[j] = fmaf(wa.y, xr[j].y, ta[j]);
        pa[j] = fmaf(wb.y, xr[j].y, pa[j]);
        ga[j] = fmaf(wc.y, xr[j].y, ga[j]);
        ta[j] = fmaf(wa.z, xr[j].z, ta[j]);
        pa[j] = fmaf(wb.z, xr[j].z, pa[j]);
        ga[j] = fmaf(wc.z, xr[j].z, ga[j]);
        ta[j] = fmaf(wa.w, xr[j].w, ta[j]);
        pa[j] = fmaf(wb.w, xr[j].w, pa[j]);
        ga[j] = fmaf(wc.w, xr[j].w, ga[j]);
      }
    }
#pragma unroll
    for (int j = 0; j < 4; ++j) {
      attp += pa[j] * ga[j];
      tS[r][tile * 64 + sg * 4 + j] = ta[j];
    }
    __syncthreads();
  }
  float attv = blocksum(attp, red, t);
  int s = t;
  float yv[32];
#pragma unroll
  for (int o = 0; o < 32; ++o) yv[o] = 0.f;
  for (int c = 0; c < 16; ++c) {
    float tv = attv * tS[c][s];
#pragma unroll
    for (int o = 0; o < 32; ++o) yv[o] = fmaf(wzs[o][c], tv, yv[o]);
  }
  float ls = 0.f;
#pragma unroll
  for (int o = 0; o < 32; ++o) ls += yv[o];
  float mu = blocksum(ls, red, t) * (1.f / 8192.f);
  float lq = 0.f;
#pragma unroll
  for (int o = 0; o < 32; ++o) { float d = yv[o] - mu; lq = fmaf(d, d, lq); }
  float var = blocksum(lq, red, t) * (1.f / 8192.f);
  float rs = rsqrtf(var + 1e-5f);
  const float* xrow = xT + ((size_t)b * Sx + s) * 128 + g * 32;
  float* yrow = yT + ((size_t)b * Sx + s) * 128 + g * 32;
#pragma unroll
  for (int o = 0; o < 32; ++o) {
    int ch = g * 32 + o;
    yrow[o] = (yv[o] - mu) * rs * gngF[ch] + gnbF[ch] + xrow[o];
  }
}

// ---------------- FFN + box-head output assembly (b128 LDS reads via c-chunking) ----------------
__global__ __launch_bounds__(256) void k_ffn(const float* __restrict__ yT,
                                             const float* __restrict__ c1T, const float* __restrict__ d1,
                                             const float* __restrict__ c2T, const float* __restrict__ d2,
                                             const float* __restrict__ c3T, const float* __restrict__ c3bF,
                                             const float* __restrict__ nxyz,
                                             void* __restrict__ outp,
                                             const int* __restrict__ flagp) {
  __shared__ __align__(16) float ys[32][132];
  __shared__ __align__(16) float h1s[32][132];
  __shared__ __align__(16) float h2s[32][132];
  __shared__ float nets[32][44];
  int bf = *flagp;
  int b = blockIdx.y, s0 = blockIdx.x * 32, t = threadIdx.x;
  {
    int r = t >> 3, part = (t & 7) * 16;
    const float4* src = (const float4*)(yT + ((size_t)b * Sx + s0 + r) * 128 + part);
#pragma unroll
    for (int q = 0; q < 4; ++q) *(float4*)&ys[r][part + q * 4] = src[q];
  }
  __syncthreads();
  int o0 = (t & 31) * 4, sl0 = (t >> 5) * 4;
  float acc[16];
#pragma unroll
  for (int k = 0; k < 16; ++k) acc[k] = 0.f;
  for (int c4 = 0; c4 < 32; ++c4) {
    float4 yv[4];
#pragma unroll
    for (int j = 0; j < 4; ++j) yv[j] = *(const float4*)&ys[sl0 + j][c4 * 4];
#pragma unroll
    for (int cc = 0; cc < 4; ++cc) {
      float4 wv = *(const float4*)(c1T + (c4 * 4 + cc) * 128 + o0);
      float yj[4] = {yv[0][cc], yv[1][cc], yv[2][cc], yv[3][cc]};
#pragma unroll
      for (int j = 0; j < 4; ++j) {
        acc[0 * 4 + j] = fmaf(wv.x, yj[j], acc[0 * 4 + j]);
        acc[1 * 4 + j] = fmaf(wv.y, yj[j], acc[1 * 4 + j]);
        acc[2 * 4 + j] = fmaf(wv.z, yj[j], acc[2 * 4 + j]);
        acc[3 * 4 + j] = fmaf(wv.w, yj[j], acc[3 * 4 + j]);
      }
    }
  }
  {
    float4 dv = *(const float4*)(d1 + o0);
    float db[4] = {dv.x, dv.y, dv.z, dv.w};
#pragma unroll
    for (int i = 0; i < 4; ++i)
#pragma unroll
      for (int j = 0; j < 4; ++j)
        h1s[sl0 + j][o0 + i] = fmaxf(acc[i * 4 + j] + db[i], 0.f);
  }
  __syncthreads();
#pragma unroll
  for (int k = 0; k < 16; ++k) acc[k] = 0.f;
  for (int c4 = 0; c4 < 32; ++c4) {
    float4 yv[4];
#pragma unroll
    for (int j = 0; j < 4; ++j) yv[j] = *(const float4*)&h1s[sl0 + j][c4 * 4];
#pragma unroll
    for (int cc = 0; cc < 4; ++cc) {
      float4 wv = *(const float4*)(c2T + (c4 * 4 + cc) * 128 + o0);
      float yj[4] = {yv[0][cc], yv[1][cc], yv[2][cc], yv[3][cc]};
#pragma unroll
      for (int j = 0; j < 4; ++j) {
        acc[0 * 4 + j] = fmaf(wv.x, yj[j], acc[0 * 4 + j]);
        acc[1 * 4 + j] = fmaf(wv.y, yj[j], acc[1 * 4 + j]);
        acc[2 * 4 + j] = fmaf(wv.z, yj[j], acc[2 * 4 + j]);
        acc[3 * 4 + j] = fmaf(wv.w, yj[j], acc[3 * 4 + j]);
      }
    }
  }
  {
    float4 dv = *(const float4*)(d2 + o0);
    float db[4] = {dv.x, dv.y, dv.z, dv.w};
#pragma unroll
    for (int i = 0; i < 4; ++i)
#pragma unroll
      for (int j = 0; j < 4; ++j)
        h2s[sl0 + j][o0 + i] = fmaxf(acc[i * 4 + j] + db[i], 0.f);
  }
  __syncthreads();
  for (int f = t; f < 43 * 32; f += 256) {
    int o = f >> 5, s = f & 31;
    float a = c3bF[o];
    for (int c4 = 0; c4 < 32; ++c4) {
      float4 hv = *(const float4*)&h2s[s][c4 * 4];
      a = fmaf(hv.x, c3T[(c4 * 4 + 0) * 43 + o], a);
      a = fmaf(hv.y, c3T[(c4 * 4 + 1) * 43 + o], a);
      a = fmaf(hv.z, c3T[(c4 * 4 + 2) * 43 + o], a);
      a = fmaf(hv.w, c3T[(c4 * 4 + 3) * 43 + o], a);
    }
    nets[s][o] = a;
  }
  __syncthreads();
  const float PI12 = (float)(M_PI / 12.0);
  for (int f = t; f < 55 * 32; f += 256) {
    int s = f / 55, kk = f - s * 55;
    float v;
    if (kk < 5) {
      v = nets[s][kk];
      if (kk >= 2) v += nxyz[((size_t)b * Sx + s0 + s) * 3 + (kk - 2)];
    } else if (kk < 31) v = nets[s][kk];
    else if (kk < 43) v = nets[s][kk - 12] * PI12;
    else v = nets[s][kk - 12];
    size_t oi = ((size_t)b * Sx + s0 + s) * 55 + kk;
    if (bf) ((u16*)outp)[oi] = f2b(v);
    else    ((float*)outp)[oi] = v;
  }
}

extern "C" void kernel_launch(void* const* d_in, const int* in_sizes, int n_in,
                              void* d_out, int out_size, void* d_ws, size_t ws_size,
                              hipStream_t stream) {
  char* w = (char*)d_ws;
  u16*   featT = (u16*)(w + OFF_FEATT);
  float* xT    = (float*)(w + OFF_XT);
  float* yT    = (float*)(w + OFF_YT);
  float* nxyz  = (float*)(w + OFF_NXYZ);
  u16*   w0F   = (u16*)(w + OFF_W0F);
  float* b0    = (float*)(w + OFF_B0);
  u16*   w1F   = (u16*)(w + OFF_W1F);
  float* b1    = (float*)(w + OFF_B1);
  u16*   w2F   = (u16*)(w + OFF_W2F);
  float* b2    = (float*)(w + OFF_B2);
  float* wtT   = (float*)(w + OFF_WTT);
  float* wpT   = (float*)(w + OFF_WPT);
  float* wgT   = (float*)(w + OFF_WGT);
  float* c1T   = (float*)(w + OFF_C1T);
  float* d1    = (float*)(w + OFF_D1);
  float* c2T   = (float*)(w + OFF_C2T);
  float* d2    = (float*)(w + OFF_D2);
  float* c3T   = (float*)(w + OFF_C3T);
  float* wzF   = (float*)(w + OFF_WZF);
  float* gngF  = (float*)(w + OFF_GNG);
  float* gnbF  = (float*)(w + OFF_GNB);
  float* c3bF  = (float*)(w + OFF_C3B);
  int*   flag  = (int*)(w + OFF_FLAG);

  k_sniff<<<1, 256, 0, stream>>>((const u32*)d_in[0], flag);
  k_mega<<<Bx + TRANS_BLKS + 64, 256, 0, stream>>>(
      d_in[0], d_in[1],
      d_in[2], d_in[3], d_in[4], d_in[5], d_in[6], d_in[7], d_in[8],
      d_in[9], d_in[10], d_in[11], d_in[12], d_in[13], d_in[14],
      d_in[15], d_in[16], d_in[17], d_in[18], d_in[19], d_in[20],
      d_in[21], d_in[22], d_in[23], d_in[24], d_in[25], d_in[26],
      d_in[27], d_in[28],
      nxyz, featT,
      w0F, b0, w1F, b1, w2F, b2, wtT, wpT, wgT,
      c1T, d1, c2T, d2, c3T, wzF, gngF, gnbF, c3bF, flag);
  k_fused<<<dim3(Sx / 8, Bx), 256, 0, stream>>>(featT, d_in[0], nxyz,
                                                w0F, b0, w1F, b1, w2F, b2, xT, flag);
  k_tpgn<<<dim3(4, Bx), 256, 0, stream>>>(xT, wtT, wpT, wgT, wzF, gngF, gnbF, yT);
  k_ffn<<<dim3(8, Bx), 256, 0, stream>>>(yT, c1T, d1, c2T, d2, c3T, c3bF, nxyz,
                                         d_out, flag);
}